// Round 12
// baseline (296.229 us; speedup 1.0000x reference)
//
#include <hip/hip_runtime.h>

using bf16x8 = __attribute__((ext_vector_type(8))) short;
using short8 = __attribute__((ext_vector_type(8))) short;
using s16x4  = __attribute__((ext_vector_type(4))) short;
using f32x4  = __attribute__((ext_vector_type(4))) float;
using u32x4  = __attribute__((ext_vector_type(4))) unsigned;
using ull    = unsigned long long;

#define T_SEQ 512
#define MFMA(A, B, C) __builtin_amdgcn_mfma_f32_16x16x32_bf16((A), (B), (C), 0, 0, 0)

// Raw barrier: lgkmcnt(0) makes this wave's ds_write visible; s_barrier has no
// vmcnt-drain. sched_barrier(0) pins ordering around the pair (rule #18).
#define BARRIER()                                            \
    do {                                                     \
        __builtin_amdgcn_sched_barrier(0);                   \
        asm volatile("s_waitcnt lgkmcnt(0)" ::: "memory");   \
        __builtin_amdgcn_s_barrier();                        \
        __builtin_amdgcn_sched_barrier(0);                   \
    } while (0)

static constexpr float NL2E  = -1.44269504f;   // -log2(e)
static constexpr float N2L2E = -2.88539008f;   // -2*log2(e)

// Truncation split: hi = bf16-truncate(v), lo = bf16-truncate(v - hi) (residual exact).
__device__ __forceinline__ void split8_tr(f32x4 a, f32x4 b, bf16x8& hi, bf16x8& lo) {
    u32x4 ua = __builtin_bit_cast(u32x4, a);
    u32x4 ub = __builtin_bit_cast(u32x4, b);
    u32x4 m  = {0xffff0000u, 0xffff0000u, 0xffff0000u, 0xffff0000u};
    f32x4 ra = a - __builtin_bit_cast(f32x4, ua & m);
    f32x4 rb = b - __builtin_bit_cast(f32x4, ub & m);
    short8 sa  = __builtin_bit_cast(short8, a);
    short8 sb  = __builtin_bit_cast(short8, b);
    short8 sra = __builtin_bit_cast(short8, ra);
    short8 srb = __builtin_bit_cast(short8, rb);
    hi = __builtin_shufflevector(sa, sb, 1, 3, 5, 7, 9, 11, 13, 15);
    lo = __builtin_shufflevector(sra, srb, 1, 3, 5, 7, 9, 11, 13, 15);
}

__device__ __forceinline__ void split4_tr(f32x4 a, s16x4& hi, s16x4& lo) {
    u32x4 ua = __builtin_bit_cast(u32x4, a);
    u32x4 m  = {0xffff0000u, 0xffff0000u, 0xffff0000u, 0xffff0000u};
    f32x4 ra = a - __builtin_bit_cast(f32x4, ua & m);
    short8 sa  = __builtin_bit_cast(short8, a);
    short8 sra = __builtin_bit_cast(short8, ra);
    hi = __builtin_shufflevector(sa, sa, 1, 3, 5, 7);
    lo = __builtin_shufflevector(sra, sra, 1, 3, 5, 7);
}

// Assemble a B-frag from two 8B halves: lo8 -> elements 0..3, hi8 -> 4..7.
__device__ __forceinline__ bf16x8 combine8(ull lo8, ull hi8) {
    u32x4 v = {(unsigned)lo8, (unsigned)(lo8 >> 32),
               (unsigned)hi8, (unsigned)(hi8 >> 32)};
    return __builtin_bit_cast(bf16x8, v);
}
// own half goes at position m (0 -> elements 0..3, 1 -> 4..7)
__device__ __forceinline__ bf16x8 combine8_sel(ull own, ull other, int m) {
    return combine8(m ? other : own, m ? own : other);
}

// 9-MFMA product block: 3 independent acc chains (hiW*hi, hiW*lo, loW*hi).
__device__ __forceinline__ void mfma9(const bf16x8 (&WH)[3], const bf16x8 (&WL)[3],
                                      bf16x8 inh, bf16x8 inl,
                                      f32x4 c0, f32x4 c1, f32x4 c2,
                                      f32x4& a0, f32x4& a1, f32x4& a2) {
    a0 = MFMA(WH[0], inh, c0); a1 = MFMA(WH[1], inh, c1); a2 = MFMA(WH[2], inh, c2);
    a0 = MFMA(WH[0], inl, a0); a1 = MFMA(WH[1], inl, a1); a2 = MFMA(WH[2], inl, a2);
    a0 = MFMA(WL[0], inh, a0); a1 = MFMA(WL[1], inh, a1); a2 = MFMA(WL[2], inh, a2);
}

// Gates for this wave's 4 hidden units; level-major 4-wide.
__device__ __forceinline__ void gate4(f32x4 aR, f32x4 aZ, f32x4 iN, f32x4 sN,
                                      float (&hf)[4]) {
    float er[4], ez[4];
    #pragma unroll
    for (int j = 0; j < 4; ++j) er[j] = __builtin_amdgcn_exp2f(aR[j] * NL2E);
    #pragma unroll
    for (int j = 0; j < 4; ++j) ez[j] = __builtin_amdgcn_exp2f(aZ[j] * NL2E);
    float gr[4], gz[4];
    #pragma unroll
    for (int j = 0; j < 4; ++j) gr[j] = __builtin_amdgcn_rcpf(1.f + er[j]);
    #pragma unroll
    for (int j = 0; j < 4; ++j) gz[j] = __builtin_amdgcn_rcpf(1.f + ez[j]);
    float en[4];
    #pragma unroll
    for (int j = 0; j < 4; ++j) {
        float u = fmaf(gr[j], sN[j], iN[j]);
        en[j] = __builtin_amdgcn_exp2f(fminf(u * N2L2E, 126.f));
    }
    float qn[4];
    #pragma unroll
    for (int j = 0; j < 4; ++j) qn[j] = __builtin_amdgcn_rcpf(1.f + en[j]);
    #pragma unroll
    for (int j = 0; j < 4; ++j) {
        float nn = fmaf(en[j] * qn[j], -2.f, 1.f);
        hf[j] = fmaf(gz[j], hf[j] - nn, nn);
    }
}

// Block = 256 threads = 4 waves = (layer L, row-half m). Own output half stays
// in registers; only the other 8B half round-trips LDS.
// VGPR=80 in R9-11 proved the allocator remats weight frags from global inside
// the loop (48 weight VGPRs can't fit in 80) -> ~200cyc L1 reloads ON the
// recurrence chain. Demand here is only ~130 < 256, so asm pins (establish +
// in-loop) force true residency without the R6 AGPR/spill fiasco.
__global__ __launch_bounds__(256, 1)
void gru2_quad(const float* __restrict__ x,
               const float* __restrict__ W_ih0, const float* __restrict__ W_hh0,
               const float* __restrict__ b_ih0, const float* __restrict__ b_hh0,
               const float* __restrict__ W_ih1, const float* __restrict__ W_hh1,
               const float* __restrict__ b_ih1, const float* __restrict__ b_hh1,
               const float* __restrict__ W_proj, const float* __restrict__ b_proj,
               float* __restrict__ out)
{
    const int tid  = threadIdx.x;
    const int wid  = tid >> 6;
    const int L    = wid >> 1;        // 0: layer0, 1: layer1
    const int m    = wid & 1;         // row half
    const int lane = tid & 63;
    const int r16  = lane & 15;
    const int q    = lane >> 4;
    const int b0   = blockIdx.x * 16;

    // [half][layer][parity][lane] (8B each) -> 2KB + 2KB
    __shared__ ull pubH_[2][2][2][64];
    __shared__ ull pubL_[2][2][2][64];

    const float* Wx = L ? W_ih1 : W_ih0;
    const float* Wh = L ? W_hh1 : W_hh0;
    const float* bx = L ? b_ih1 : b_ih0;
    const float* bh = L ? b_hh1 : b_hh0;

    // weight fragments for tiles {m, 2+m, 4+m}; g: 0=r, 1=z, 2=n
    bf16x8 WxH[3], WxL[3], WhH[3], WhL[3];
    f32x4 bxf[3], bhf[3];
    #pragma unroll
    for (int g = 0; g < 3; ++g) {
        const int tile = 2 * g + m;
        const float* p1 = Wx + (16 * tile + r16) * 32 + 4 * q;
        split8_tr(*(const f32x4*)p1, *(const f32x4*)(p1 + 16), WxH[g], WxL[g]);
        const float* p2 = Wh + (16 * tile + r16) * 32 + 4 * q;
        split8_tr(*(const f32x4*)p2, *(const f32x4*)(p2 + 16), WhH[g], WhL[g]);
        bxf[g] = *(const f32x4*)(bx + 16 * tile + 4 * q);
        bhf[g] = *(const f32x4*)(bh + 16 * tile + 4 * q);
    }

    // establish residency (opaque defs the allocator can't look through)
    #pragma unroll
    for (int g = 0; g < 3; ++g) {
        asm volatile("" : "+v"(WxH[g]), "+v"(WxL[g]));
        asm volatile("" : "+v"(WhH[g]), "+v"(WhL[g]));
        asm volatile("" : "+v"(bxf[g]), "+v"(bhf[g]));
    }

    float hf[4] = {0.f, 0.f, 0.f, 0.f};
    ull ownH = 0, ownL = 0;                    // this wave's 4 h values, hi/lo bf16
    const float* xp = x + (size_t)(b0 + r16) * (T_SEQ * 32) + 4 * q;
    f32x4 xA = {}, xB = {};
    bf16x8 xh_cur = {}, xl_cur = {};

    if (L == 0) {
        f32x4 x0A = *(const f32x4*)(xp);
        f32x4 x0B = *(const f32x4*)(xp + 16);
        xA = *(const f32x4*)(xp + 32);         // x[1] in flight
        xB = *(const f32x4*)(xp + 48);
        split8_tr(x0A, x0B, xh_cur, xl_cur);   // x[0]
        // prologue: h0[0] from x[0], state = 0 (state accs = b_hh frags)
        f32x4 iR, iZ, iN;
        mfma9(WxH, WxL, xh_cur, xl_cur, bxf[0], bxf[1], bxf[2], iR, iZ, iN);
        gate4(iR + bhf[0], iZ + bhf[1], iN, bhf[2], hf);
        s16x4 hi4, lo4;
        split4_tr(f32x4{hf[0], hf[1], hf[2], hf[3]}, hi4, lo4);
        ownH = __builtin_bit_cast(ull, hi4);
        ownL = __builtin_bit_cast(ull, lo4);
        pubH_[m][0][0][lane] = ownH;           // publish h0[0] half
        pubL_[m][0][0][lane] = ownL;
        split8_tr(xA, xB, xh_cur, xl_cur);     // x[1] -> cur for iter 1
        xA = *(const f32x4*)(xp + 64);         // x[2] in flight
        xB = *(const f32x4*)(xp + 80);
    } else {
        // zero h1's initial state slot (read at t=1 as parity 1)
        pubH_[m][1][1][lane] = 0;
        pubL_[m][1][1][lane] = 0;
    }

    // ---- main loop: wave (0,m) -> h0[t] half, wave (1,m) -> h1[t-1] half ----
    #pragma unroll 1
    for (int t = 1; t < T_SEQ; ++t) {
        // in-loop pins: remat-through-the-backedge is illegal; weights/biases
        // must stay in VGPRs across iterations. Emits no instructions.
        #pragma unroll
        for (int g = 0; g < 3; ++g) {
            asm volatile("" : "+v"(WxH[g]), "+v"(WxL[g]));
            asm volatile("" : "+v"(WhH[g]), "+v"(WhL[g]));
            asm volatile("" : "+v"(bxf[g]), "+v"(bhf[g]));
        }

        BARRIER();                       // prev-iter LDS pubs visible; no vmcnt drain
        const int pPrev = (t - 1) & 1;
        const int pCur  = t & 1;
        f32x4 iR, iZ, iN, sR, sZ, sN;
        if (L == 0) {
            ull oH = pubH_[1 - m][0][pPrev][lane];     // other h0 half (8B)
            ull oL = pubL_[1 - m][0][pPrev][lane];
            // input MFMAs start immediately: xh_cur pre-split last iteration
            mfma9(WxH, WxL, xh_cur, xl_cur, bxf[0], bxf[1], bxf[2], iR, iZ, iN);
            bf16x8 Sh = combine8_sel(ownH, oH, m);     // waits lgkmcnt here
            bf16x8 Sl = combine8_sel(ownL, oL, m);
            mfma9(WhH, WhL, Sh, Sl, bhf[0], bhf[1], bhf[2], sR, sZ, sN);
            split8_tr(xA, xB, xh_cur, xl_cur);         // x[t+1] (load 1 iter old)
            const int tn = (t + 2 < T_SEQ) ? t + 2 : T_SEQ - 1;
            xA = *(const f32x4*)(xp + (size_t)tn * 32);    // x[t+2] in flight
            xB = *(const f32x4*)(xp + (size_t)tn * 32 + 16);
        } else {
            ull i0H = pubH_[0][0][pPrev][lane];        // h0[t-1] halves (input)
            ull i1H = pubH_[1][0][pPrev][lane];
            ull i0L = pubL_[0][0][pPrev][lane];
            ull i1L = pubL_[1][0][pPrev][lane];
            ull oH  = pubH_[1 - m][1][pCur][lane];     // other h1[t-2] half
            ull oL  = pubL_[1 - m][1][pCur][lane];
            bf16x8 inh = combine8(i0H, i1H);
            bf16x8 inl = combine8(i0L, i1L);
            mfma9(WxH, WxL, inh, inl, bxf[0], bxf[1], bxf[2], iR, iZ, iN);
            bf16x8 Sh = combine8_sel(ownH, oH, m);
            bf16x8 Sl = combine8_sel(ownL, oL, m);
            mfma9(WhH, WhL, Sh, Sl, bhf[0], bhf[1], bhf[2], sR, sZ, sN);
        }

        gate4(sR + iR, sZ + iZ, iN, sN, hf);

        s16x4 hi4, lo4;
        split4_tr(f32x4{hf[0], hf[1], hf[2], hf[3]}, hi4, lo4);
        ownH = __builtin_bit_cast(ull, hi4);
        ownL = __builtin_bit_cast(ull, lo4);
        const int pW = (L == 0) ? pCur : pPrev;   // L0 writes h0[t], L1 h1[t-1]
        pubH_[m][L][pW][lane] = ownH;
        pubL_[m][L][pW][lane] = ownL;
    }

    __syncthreads();                     // h0[511] (p1), h1[510] (p0) visible
    if (L == 1) {
        // final step: h1[511] from h0[511] and h1[510]
        bf16x8 inh = combine8(pubH_[0][0][1][lane], pubH_[1][0][1][lane]);
        bf16x8 inl = combine8(pubL_[0][0][1][lane], pubL_[1][0][1][lane]);
        bf16x8 Sh  = combine8_sel(ownH, pubH_[1 - m][1][0][lane], m);
        bf16x8 Sl  = combine8_sel(ownL, pubL_[1 - m][1][0][lane], m);
        f32x4 iR, iZ, iN, sR, sZ, sN;
        mfma9(WxH, WxL, inh, inl, bxf[0], bxf[1], bxf[2], iR, iZ, iN);
        mfma9(WhH, WhL, Sh, Sl, bhf[0], bhf[1], bhf[2], sR, sZ, sN);
        gate4(sR + iR, sZ + iZ, iN, sN, hf);
        s16x4 hi4, lo4;
        split4_tr(f32x4{hf[0], hf[1], hf[2], hf[3]}, hi4, lo4);
        pubH_[m][1][1][lane] = __builtin_bit_cast(ull, hi4);   // h1[511]
        pubL_[m][1][1][lane] = __builtin_bit_cast(ull, lo4);
    }
    __syncthreads();

    if (wid == 2) {
        // projection: out[b][o] = b_proj[o] + sum_u W_proj[o][u] * h1[u]
        bf16x8 Hh = combine8(pubH_[0][1][1][lane], pubH_[1][1][1][lane]);
        bf16x8 Hl = combine8(pubL_[0][1][1][lane], pubL_[1][1][1][lane]);
        const float* pp = W_proj + r16 * 32 + 4 * q;
        bf16x8 Wph, Wpl;
        split8_tr(*(const f32x4*)pp, *(const f32x4*)(pp + 16), Wph, Wpl);
        f32x4 accp = *(const f32x4*)(b_proj + 4 * q);   // elem reg -> output 4q+reg
        accp = MFMA(Wph, Hh, accp);
        accp = MFMA(Wph, Hl, accp);
        accp = MFMA(Wpl, Hh, accp);
        #pragma unroll
        for (int rg = 0; rg < 4; ++rg)
            out[(b0 + r16) * 16 + 4 * q + rg] = accp[rg];
    }
}

extern "C" void kernel_launch(void* const* d_in, const int* in_sizes, int n_in,
                              void* d_out, int out_size, void* d_ws, size_t ws_size,
                              hipStream_t stream) {
    const float* x      = (const float*)d_in[0];
    const float* W_ih0  = (const float*)d_in[1];
    const float* W_hh0  = (const float*)d_in[2];
    const float* b_ih0  = (const float*)d_in[3];
    const float* b_hh0  = (const float*)d_in[4];
    const float* W_ih1  = (const float*)d_in[5];
    const float* W_hh1  = (const float*)d_in[6];
    const float* b_ih1  = (const float*)d_in[7];
    const float* b_hh1  = (const float*)d_in[8];
    const float* W_proj = (const float*)d_in[9];
    const float* b_proj = (const float*)d_in[10];
    float* out = (float*)d_out;

    const int nb   = in_sizes[0] / (T_SEQ * 32);   // 4096 batch elements
    const int grid = nb / 16;                      // 16 batches per 4-wave block

    hipLaunchKernelGGL(gru2_quad, dim3(grid), dim3(256), 0, stream,
                       x, W_ih0, W_hh0, b_ih0, b_hh0,
                       W_ih1, W_hh1, b_ih1, b_hh1, W_proj, b_proj, out);
}

// Round 13
// 282.158 us; speedup vs baseline: 1.0499x; 1.0499x over previous
//
#include <hip/hip_runtime.h>

using bf16x8 = __attribute__((ext_vector_type(8))) short;
using short8 = __attribute__((ext_vector_type(8))) short;
using s16x4  = __attribute__((ext_vector_type(4))) short;
using f32x4  = __attribute__((ext_vector_type(4))) float;
using u32x4  = __attribute__((ext_vector_type(4))) unsigned;
using ull    = unsigned long long;

#define T_SEQ 512
#define NITER 514
#define MFMA(A, B, C) __builtin_amdgcn_mfma_f32_16x16x32_bf16((A), (B), (C), 0, 0, 0)

// Raw barrier: lgkmcnt(0) makes this wave's ds_write visible; no vmcnt drain.
#define BARRIER()                                            \
    do {                                                     \
        __builtin_amdgcn_sched_barrier(0);                   \
        asm volatile("s_waitcnt lgkmcnt(0)" ::: "memory");   \
        __builtin_amdgcn_s_barrier();                        \
        __builtin_amdgcn_sched_barrier(0);                   \
    } while (0)

static constexpr float NL2E  = -1.44269504f;   // -log2(e)
static constexpr float N2L2E = -2.88539008f;   // -2*log2(e)

// Truncation split: hi = bf16-truncate(v), lo = bf16-truncate(v - hi) (exact residual).
__device__ __forceinline__ void split8_tr(f32x4 a, f32x4 b, bf16x8& hi, bf16x8& lo) {
    u32x4 ua = __builtin_bit_cast(u32x4, a);
    u32x4 ub = __builtin_bit_cast(u32x4, b);
    u32x4 m  = {0xffff0000u, 0xffff0000u, 0xffff0000u, 0xffff0000u};
    f32x4 ra = a - __builtin_bit_cast(f32x4, ua & m);
    f32x4 rb = b - __builtin_bit_cast(f32x4, ub & m);
    short8 sa  = __builtin_bit_cast(short8, a);
    short8 sb  = __builtin_bit_cast(short8, b);
    short8 sra = __builtin_bit_cast(short8, ra);
    short8 srb = __builtin_bit_cast(short8, rb);
    hi = __builtin_shufflevector(sa, sb, 1, 3, 5, 7, 9, 11, 13, 15);
    lo = __builtin_shufflevector(sra, srb, 1, 3, 5, 7, 9, 11, 13, 15);
}

__device__ __forceinline__ void split4_tr(f32x4 a, s16x4& hi, s16x4& lo) {
    u32x4 ua = __builtin_bit_cast(u32x4, a);
    u32x4 m  = {0xffff0000u, 0xffff0000u, 0xffff0000u, 0xffff0000u};
    f32x4 ra = a - __builtin_bit_cast(f32x4, ua & m);
    short8 sa  = __builtin_bit_cast(short8, a);
    short8 sra = __builtin_bit_cast(short8, ra);
    hi = __builtin_shufflevector(sa, sa, 1, 3, 5, 7);
    lo = __builtin_shufflevector(sra, sra, 1, 3, 5, 7);
}

__device__ __forceinline__ bf16x8 combine8(ull lo8, ull hi8) {
    u32x4 v = {(unsigned)lo8, (unsigned)(lo8 >> 32),
               (unsigned)hi8, (unsigned)(hi8 >> 32)};
    return __builtin_bit_cast(bf16x8, v);
}
__device__ __forceinline__ bf16x8 combine8_sel(ull own, ull other, int m) {
    return combine8(m ? other : own, m ? own : other);
}

// Gates for 4 hidden units. aR/aZ: full r/z pre-acts; iN: input-side n (+b_ihn);
// sN: state-side n (+b_hhn). Level-major.
__device__ __forceinline__ void gate4(f32x4 aR, f32x4 aZ, f32x4 iN, f32x4 sN,
                                      float (&hf)[4]) {
    float er[4], ez[4];
    #pragma unroll
    for (int j = 0; j < 4; ++j) er[j] = __builtin_amdgcn_exp2f(aR[j] * NL2E);
    #pragma unroll
    for (int j = 0; j < 4; ++j) ez[j] = __builtin_amdgcn_exp2f(aZ[j] * NL2E);
    float gr[4], gz[4];
    #pragma unroll
    for (int j = 0; j < 4; ++j) gr[j] = __builtin_amdgcn_rcpf(1.f + er[j]);
    #pragma unroll
    for (int j = 0; j < 4; ++j) gz[j] = __builtin_amdgcn_rcpf(1.f + ez[j]);
    float en[4];
    #pragma unroll
    for (int j = 0; j < 4; ++j) {
        float u = fmaf(gr[j], sN[j], iN[j]);
        en[j] = __builtin_amdgcn_exp2f(fminf(u * N2L2E, 126.f));
    }
    float qn[4];
    #pragma unroll
    for (int j = 0; j < 4; ++j) qn[j] = __builtin_amdgcn_rcpf(1.f + en[j]);
    #pragma unroll
    for (int j = 0; j < 4; ++j) {
        float nn = fmaf(en[j] * qn[j], -2.f, 1.f);
        hf[j] = fmaf(gz[j], hf[j] - nn, nn);
    }
}

// Block = 512 threads = 8 waves = (role, L, m). role 0 = state (recurrence),
// role 1 = input (projections, known >=1 interval ahead). L1 runs at lag 2 so
// EVERY LDS read is of data published a full interval earlier -> no
// intra-interval deps. 2 waves/SIMD (state+input pair) -> TLP fills the
// recurrence chain's stall cycles (1 wave/SIMD structures R9-R12 could not).
// Schedule at interval t: L0-in: I0(t+1)=Wih0*x[t+1]; L0-st: h0[t];
// L1-in: I1(t-1)=Wih1*h0[t-1]; L1-st: h1[t-2]. 514 intervals total.
// Frag map: batch=b0+(lane&15), q=lane>>4; elems 0..3 = units 4q+j, 4..7 =
// 16+4q+j. D: col=lane&15, row=4q+reg (m89).
__global__ __launch_bounds__(512, 1)
void gru2_octo(const float* __restrict__ x,
               const float* __restrict__ W_ih0, const float* __restrict__ W_hh0,
               const float* __restrict__ b_ih0, const float* __restrict__ b_hh0,
               const float* __restrict__ W_ih1, const float* __restrict__ W_hh1,
               const float* __restrict__ b_ih1, const float* __restrict__ b_hh1,
               const float* __restrict__ W_proj, const float* __restrict__ b_proj,
               float* __restrict__ out)
{
    const int tid  = threadIdx.x;
    const int wid  = tid >> 6;
    const int role = wid >> 2;        // 0: state wave, 1: input wave
    const int L    = (wid >> 1) & 1;  // layer
    const int m    = wid & 1;         // row half
    const int lane = tid & 63;
    const int r16  = lane & 15;
    const int q    = lane >> 4;
    const int b0   = blockIdx.x * 16;

    // h publications: [m][L][parity][lane], 8B halves (2KB + 2KB)
    __shared__ ull pubH_[2][2][2][64];
    __shared__ ull pubL_[2][2][2][64];
    // input-side acc publications: [L][m][parity][lane][chain r/z/n] (24KB)
    // lane stride 48B -> conflict-free ds_read_b128 (3 coprime with banks)
    __shared__ f32x4 iacc[2][2][2][64][3];

    if (role == 0) {
        // ================= STATE WAVE (L, m) =================
        const float* Wh = L ? W_hh1 : W_hh0;
        const float* bh = L ? b_hh1 : b_hh0;
        bf16x8 WhH[3], WhL[3];
        #pragma unroll
        for (int g = 0; g < 3; ++g) {
            const int tile = 2 * g + m;
            const float* p2 = Wh + (16 * tile + r16) * 32 + 4 * q;
            split8_tr(*(const f32x4*)p2, *(const f32x4*)(p2 + 16), WhH[g], WhL[g]);
        }
        f32x4 bhn = *(const f32x4*)(bh + 16 * (4 + m) + 4 * q);   // n-gate b_hh

        // zero the parity-1 state slot (read as h[-1] other-half)
        pubH_[m][L][1][lane] = 0;
        pubL_[m][L][1][lane] = 0;

        float hf[4] = {0.f, 0.f, 0.f, 0.f};
        ull ownH = 0, ownL = 0;
        const int t0 = L ? 2 : 0;
        const int t1 = L ? (NITER - 1) : (T_SEQ - 1);

        #pragma unroll 1
        for (int t = 0; t < NITER; ++t) {
            BARRIER();
            if (t < t0 || t > t1) continue;
            const int pR = (t - 1) & 1;          // other-half state parity
            const int pC = t & 1;                // iacc read + pub write parity
            ull oH = pubH_[1 - m][L][pR][lane];
            ull oL = pubL_[1 - m][L][pR][lane];
            f32x4 cR = iacc[L][m][pC][lane][0];  // rz arrive pre-biased+summed
            f32x4 cZ = iacc[L][m][pC][lane][1];
            f32x4 cN = iacc[L][m][pC][lane][2];
            bf16x8 Sh = combine8_sel(ownH, oH, m);
            bf16x8 Sl = combine8_sel(ownL, oL, m);
            f32x4 sR = MFMA(WhH[0], Sh, cR);     // I-side folded in as C-in
            f32x4 sZ = MFMA(WhH[1], Sh, cZ);
            f32x4 sN = MFMA(WhH[2], Sh, bhn);
            sR = MFMA(WhH[0], Sl, sR); sZ = MFMA(WhH[1], Sl, sZ); sN = MFMA(WhH[2], Sl, sN);
            sR = MFMA(WhL[0], Sh, sR); sZ = MFMA(WhL[1], Sh, sZ); sN = MFMA(WhL[2], Sh, sN);
            gate4(sR, sZ, cN, sN, hf);
            s16x4 hi4, lo4;
            split4_tr(f32x4{hf[0], hf[1], hf[2], hf[3]}, hi4, lo4);
            ownH = __builtin_bit_cast(ull, hi4);
            ownL = __builtin_bit_cast(ull, lo4);
            pubH_[m][L][pC][lane] = ownH;
            pubL_[m][L][pC][lane] = ownL;
        }
    } else if (L == 0) {
        // ================= INPUT WAVE layer 0 =================
        bf16x8 WxH[3], WxL[3];
        f32x4 cRb, cZb, cNb;
        #pragma unroll
        for (int g = 0; g < 3; ++g) {
            const int tile = 2 * g + m;
            const float* p1 = W_ih0 + (16 * tile + r16) * 32 + 4 * q;
            split8_tr(*(const f32x4*)p1, *(const f32x4*)(p1 + 16), WxH[g], WxL[g]);
        }
        cRb = *(const f32x4*)(b_ih0 + 16 * m + 4 * q)
            + *(const f32x4*)(b_hh0 + 16 * m + 4 * q);              // r total bias
        cZb = *(const f32x4*)(b_ih0 + 16 * (2 + m) + 4 * q)
            + *(const f32x4*)(b_hh0 + 16 * (2 + m) + 4 * q);        // z total bias
        cNb = *(const f32x4*)(b_ih0 + 16 * (4 + m) + 4 * q);        // n: b_ih only

        const float* xp = x + (size_t)(b0 + r16) * (T_SEQ * 32) + 4 * q;
        // prologue: I0(0) published to parity 0 before first barrier
        {
            f32x4 xA0 = *(const f32x4*)(xp);
            f32x4 xB0 = *(const f32x4*)(xp + 16);
            bf16x8 xh, xl;
            split8_tr(xA0, xB0, xh, xl);
            f32x4 iR = MFMA(WxH[0], xh, cRb);
            f32x4 iZ = MFMA(WxH[1], xh, cZb);
            f32x4 iN = MFMA(WxH[2], xh, cNb);
            iR = MFMA(WxH[0], xl, iR); iZ = MFMA(WxH[1], xl, iZ); iN = MFMA(WxH[2], xl, iN);
            iR = MFMA(WxL[0], xh, iR); iZ = MFMA(WxL[1], xh, iZ); iN = MFMA(WxL[2], xh, iN);
            iacc[0][m][0][lane][0] = iR;
            iacc[0][m][0][lane][1] = iZ;
            iacc[0][m][0][lane][2] = iN;
        }
        f32x4 xA = *(const f32x4*)(xp + 32);       // x[1] in flight
        f32x4 xB = *(const f32x4*)(xp + 48);

        #pragma unroll 1
        for (int t = 0; t < NITER; ++t) {
            BARRIER();
            if (t > T_SEQ - 2) continue;           // compute I0(t+1), t+1 <= 511
            bf16x8 xh, xl;
            split8_tr(xA, xB, xh, xl);             // x[t+1]
            const int tn = (t + 2 < T_SEQ) ? t + 2 : T_SEQ - 1;
            xA = *(const f32x4*)(xp + (size_t)tn * 32);
            xB = *(const f32x4*)(xp + (size_t)tn * 32 + 16);
            f32x4 iR = MFMA(WxH[0], xh, cRb);
            f32x4 iZ = MFMA(WxH[1], xh, cZb);
            f32x4 iN = MFMA(WxH[2], xh, cNb);
            iR = MFMA(WxH[0], xl, iR); iZ = MFMA(WxH[1], xl, iZ); iN = MFMA(WxH[2], xl, iN);
            iR = MFMA(WxL[0], xh, iR); iZ = MFMA(WxL[1], xh, iZ); iN = MFMA(WxL[2], xh, iN);
            const int wp = (t + 1) & 1;
            iacc[0][m][wp][lane][0] = iR;
            iacc[0][m][wp][lane][1] = iZ;
            iacc[0][m][wp][lane][2] = iN;
        }
    } else {
        // ================= INPUT WAVE layer 1 =================
        bf16x8 WxH[3], WxL[3];
        f32x4 cRb, cZb, cNb;
        #pragma unroll
        for (int g = 0; g < 3; ++g) {
            const int tile = 2 * g + m;
            const float* p1 = W_ih1 + (16 * tile + r16) * 32 + 4 * q;
            split8_tr(*(const f32x4*)p1, *(const f32x4*)(p1 + 16), WxH[g], WxL[g]);
        }
        cRb = *(const f32x4*)(b_ih1 + 16 * m + 4 * q)
            + *(const f32x4*)(b_hh1 + 16 * m + 4 * q);
        cZb = *(const f32x4*)(b_ih1 + 16 * (2 + m) + 4 * q)
            + *(const f32x4*)(b_hh1 + 16 * (2 + m) + 4 * q);
        cNb = *(const f32x4*)(b_ih1 + 16 * (4 + m) + 4 * q);

        #pragma unroll 1
        for (int t = 0; t < NITER; ++t) {
            BARRIER();
            if (t < 1 || t > T_SEQ) continue;      // compute I1(t-1), 0..511
            const int p = (t - 1) & 1;
            bf16x8 inh = combine8(pubH_[0][0][p][lane], pubH_[1][0][p][lane]);
            bf16x8 inl = combine8(pubL_[0][0][p][lane], pubL_[1][0][p][lane]);
            f32x4 iR = MFMA(WxH[0], inh, cRb);
            f32x4 iZ = MFMA(WxH[1], inh, cZb);
            f32x4 iN = MFMA(WxH[2], inh, cNb);
            iR = MFMA(WxH[0], inl, iR); iZ = MFMA(WxH[1], inl, iZ); iN = MFMA(WxH[2], inl, iN);
            iR = MFMA(WxL[0], inh, iR); iZ = MFMA(WxL[1], inh, iZ); iN = MFMA(WxL[2], inh, iN);
            iacc[1][m][p][lane][0] = iR;
            iacc[1][m][p][lane][1] = iZ;
            iacc[1][m][p][lane][2] = iN;
        }
    }

    __syncthreads();                  // h1[511] (parity 1) visible to all
    if (wid == 0) {
        // projection: out[b][o] = b_proj[o] + sum_u W_proj[o][u] * h1[u]
        bf16x8 Hh = combine8(pubH_[0][1][1][lane], pubH_[1][1][1][lane]);
        bf16x8 Hl = combine8(pubL_[0][1][1][lane], pubL_[1][1][1][lane]);
        const float* pp = W_proj + r16 * 32 + 4 * q;
        bf16x8 Wph, Wpl;
        split8_tr(*(const f32x4*)pp, *(const f32x4*)(pp + 16), Wph, Wpl);
        f32x4 accp = *(const f32x4*)(b_proj + 4 * q);   // elem reg -> output 4q+reg
        accp = MFMA(Wph, Hh, accp);
        accp = MFMA(Wph, Hl, accp);
        accp = MFMA(Wpl, Hh, accp);
        #pragma unroll
        for (int rg = 0; rg < 4; ++rg)
            out[(b0 + r16) * 16 + 4 * q + rg] = accp[rg];
    }
}

extern "C" void kernel_launch(void* const* d_in, const int* in_sizes, int n_in,
                              void* d_out, int out_size, void* d_ws, size_t ws_size,
                              hipStream_t stream) {
    const float* x      = (const float*)d_in[0];
    const float* W_ih0  = (const float*)d_in[1];
    const float* W_hh0  = (const float*)d_in[2];
    const float* b_ih0  = (const float*)d_in[3];
    const float* b_hh0  = (const float*)d_in[4];
    const float* W_ih1  = (const float*)d_in[5];
    const float* W_hh1  = (const float*)d_in[6];
    const float* b_ih1  = (const float*)d_in[7];
    const float* b_hh1  = (const float*)d_in[8];
    const float* W_proj = (const float*)d_in[9];
    const float* b_proj = (const float*)d_in[10];
    float* out = (float*)d_out;

    const int nb   = in_sizes[0] / (T_SEQ * 32);   // 4096 batch elements
    const int grid = nb / 16;                      // 16 batches per 8-wave block

    hipLaunchKernelGGL(gru2_octo, dim3(grid), dim3(512), 0, stream,
                       x, W_ih0, W_hh0, b_ih0, b_hh0,
                       W_ih1, W_hh1, b_ih1, b_hh1, W_proj, b_proj, out);
}